// Round 8
// baseline (92.522 us; speedup 1.0000x reference)
//
#include <hip/hip_runtime.h>
#include <hip/hip_cooperative_groups.h>
#include <cstring>
#include <cstdint>

namespace cg = cooperative_groups;

#define NPTS 16384
#define FUVC 140.0f
#define R_SILF 0.008f
#define R_DEPF 0.012f
#define R2_SIL (0.008f*0.008f)
#define R2_DEP (0.012f*0.012f)
#define CH 512

// ---------------- ws layout (32-bit word offsets) ----------------
#define AREA_OFF  48
#define PA_OFF    50
#define R2ADA_OFF 52
#define TICK0     54
#define TICK1     55
#define CNT_SIL   64
#define OFF_SIL   2112
#define CNT_ADA   4160
#define OFF_ADA   6208
#define FLAGS8    8256   // tier-0/1: u8[2][16384] per-pixel any-hit (plain byte stores)
#define FLAGS     8256   // tier-2: u32[2][16384] (legacy layout, disjoint use)
#define ZERO_END  16448  // zero region = words [48, ZERO_END)
#define PROJ0     41024
#define PROJ1     172096
#define LSILF     303168                 // float4[2][65536]
#define LADAF     827456                 // float4[2][147456]
#define WS1_WORDS 2007104u
#define WS1_NEEDED ((size_t)WS1_WORDS * 4u)
#define LSIL      303168
#define LADA      434240
#define WS2_WORDS 729152u
#define WS2_NEEDED ((size_t)WS2_WORDS * 4u)

#define FUSED_BLOCKS 1024
#define FUSED_NT (FUSED_BLOCKS * 256)

// ---------------- shared device helpers ----------------
__device__ __forceinline__ void cam_calc(float elev, float azim, float c[12]) {
    const float D2R = 0.017453292519943295f;
    float er = elev * D2R, ar = azim * D2R;
    float ce = cosf(er), se = sinf(er), ca = cosf(ar), sa = sinf(ar);
    float cx = 1.2f * ce * sa, cy = 1.2f * se, cz = 1.2f * ce * ca;
    float n = sqrtf(cx*cx + cy*cy + cz*cz) + 1e-8f;
    float zx = -cx / n, zy = -cy / n, zz = -cz / n;
    float xx = zz, xy = 0.0f, xz = -zx;
    float xn = sqrtf(xx*xx + xy*xy + xz*xz) + 1e-8f;
    xx /= xn; xz /= xn;
    float yx = zy*xz - zz*xy, yy = zz*xx - zx*xz, yz = zx*xy - zy*xx;
    c[0]=xx; c[1]=xy; c[2]=xz; c[3]=yx; c[4]=yy; c[5]=yz;
    c[6]=zx; c[7]=zy; c[8]=zz;
    c[9]  = -(cx*xx + cy*xy + cz*xz);
    c[10] = -(cx*yx + cy*yy + cz*yz);
    c[11] = -(cx*zx + cy*zy + cz*zz);
}

__device__ __forceinline__ void cam_compute(const float* __restrict__ param,
                                            float* __restrict__ ws,
                                            int t, float ue0, float ue1,
                                            float ua0, float ua1) {
    int b = t >> 1, cam = t & 1;
    float azim0 = param[b * 24 + 0];
    float elev0 = param[b * 24 + 3];
    float elev, azim;
    if (cam == 0) { elev = elev0; azim = azim0; }
    else {
        float ue = b ? ue1 : ue0;
        float ua = b ? ua1 : ua0;
        elev = ue * 60.0f - 30.0f;
        azim = ua * 300.0f + azim0 + 30.0f;
    }
    float c[12];
    cam_calc(elev, azim, c);
    float* w = ws + t * 12;
    #pragma unroll
    for (int i = 0; i < 12; i++) w[i] = c[i];
}

__device__ __forceinline__ float4 project_pt(const float* __restrict__ P,
                                             const float c[12]) {
    float X = P[0], Y = P[1], Z = P[2];
    float xc = X*c[0] + Y*c[1] + Z*c[2] + c[9];
    float yc = X*c[3] + Y*c[4] + Z*c[5] + c[10];
    float zc = X*c[6] + Y*c[7] + Z*c[8] + c[11];
    float zs = zc > 1e-5f ? zc : 1.0f;
    float px = 1.0f - (FUVC * xc / zs + 64.0f) * (1.0f/64.0f);
    float py = 1.0f - (FUVC * yc / zs + 64.0f) * (1.0f/64.0f);
    return make_float4(px, py, zc, 0.0f);
}

__device__ __forceinline__ void pix_range(float p, float r, int& lo, int& hi) {
    float lo_f = (1.0f - p - r) * 64.0f - 0.5f;
    float hi_f = (1.0f - p + r) * 64.0f - 0.5f;
    lo = (int)ceilf(lo_f - 1e-3f);
    hi = (int)floorf(hi_f + 1e-3f);
    lo = max(lo, 0); hi = min(hi, 127);
}

// bbox in 4x4-pixel bin coords; empty -> byh < byl
__device__ __forceinline__ void bin_bbox(float4 q, float r, int& bxl, int& bxh,
                                         int& byl, int& byh) {
    bxl = 0; bxh = -1; byl = 0; byh = -1;
    if (q.z > 0.0f) {
        int cl, chh, rl, rh;
        pix_range(q.x, r, cl, chh);
        pix_range(q.y, r, rl, rh);
        if (cl <= chh && rl <= rh) {
            bxl = cl >> 2; bxh = chh >> 2; byl = rl >> 2; byh = rh >> 2;
        }
    }
}

__device__ __forceinline__ void top8_insert(float z, float d,
                                            float tz[8], float td[8]) {
    #pragma unroll
    for (int k = 0; k < 8; k++) {
        bool lt = z < tz[k];
        float oz = tz[k], od = td[k];
        if (lt) { tz[k] = z; td[k] = d; z = oz; d = od; }
    }
}

__device__ __forceinline__ void hit_test(float4 pt, float gx, float gy, float r2,
                                         float tz[8], float td[8]) {
    float dx = gx - pt.x, dy = gy - pt.y;
    float d2 = dx*dx + dy*dy;
    if (d2 < r2 && pt.z > 0.0f && pt.z < tz[7]) top8_insert(pt.z, d2, tz, td);
}

__device__ __forceinline__ void merge_sorted8(float tz[8], float td[8], int mask) {
    float oz[8], od[8];
    #pragma unroll
    for (int k = 0; k < 8; k++) {
        oz[k] = __shfl_xor(tz[k], mask);
        od[k] = __shfl_xor(td[k], mask);
    }
    float mz[8], md[8];
    #pragma unroll
    for (int k = 0; k < 8; k++) {
        bool take = oz[7 - k] < tz[k];
        mz[k] = take ? oz[7 - k] : tz[k];
        md[k] = take ? od[7 - k] : td[k];
    }
    #define CE(i, j) { bool sw = mz[j] < mz[i]; \
        float t1 = mz[i], t2 = md[i]; \
        mz[i] = sw ? mz[j] : mz[i]; md[i] = sw ? md[j] : md[i]; \
        mz[j] = sw ? t1 : mz[j];    md[j] = sw ? t2 : md[j]; }
    CE(0,4) CE(1,5) CE(2,6) CE(3,7)
    CE(0,2) CE(1,3) CE(4,6) CE(5,7)
    CE(0,1) CE(2,3) CE(4,5) CE(6,7)
    #undef CE
    #pragma unroll
    for (int k = 0; k < 8; k++) { tz[k] = mz[k]; td[k] = md[k]; }
}

__device__ __forceinline__ void scan1024(unsigned* uw, unsigned cbase,
                                         unsigned obase, unsigned* s, int t) {
    unsigned c0 = uw[cbase + t*4 + 0];
    unsigned c1 = uw[cbase + t*4 + 1];
    unsigned c2 = uw[cbase + t*4 + 2];
    unsigned c3 = uw[cbase + t*4 + 3];
    unsigned tot = c0 + c1 + c2 + c3;
    s[t] = tot; __syncthreads();
    for (int off = 1; off < 256; off <<= 1) {
        unsigned v = (t >= off) ? s[t - off] : 0u;
        __syncthreads();
        s[t] += v;
        __syncthreads();
    }
    unsigned base = s[t] - tot;
    uw[obase + t*4 + 0] = base;
    uw[obase + t*4 + 1] = base + c0;
    uw[obase + t*4 + 2] = base + c0 + c1;
    uw[obase + t*4 + 3] = base + c0 + c1 + c2;
    uw[cbase + t*4 + 0] = 0;
    uw[cbase + t*4 + 1] = 0;
    uw[cbase + t*4 + 2] = 0;
    uw[cbase + t*4 + 3] = 0;
}

// ---------------- device sub-bodies (split path, round-6 known-good) ----------------
__device__ __forceinline__ void body_area_scan(float* __restrict__ ws, int job,
                                               int t, unsigned* s) {
    unsigned* uw = (unsigned*)ws;
    if (job < 2) {
        int b = job;
        unsigned acc = 0;
        #pragma unroll
        for (int j = 0; j < 16; j++) {
            unsigned w = uw[FLAGS8 + b * 4096 + t * 16 + j];
            acc += __popc(w & 0x01010101u);
        }
        s[t] = acc; __syncthreads();
        for (int off = 128; off > 0; off >>= 1) {
            if (t < off) s[t] += s[t + off];
            __syncthreads();
        }
        if (t == 0) {
            unsigned area = s[0];
            uw[AREA_OFF + b] = area;
            float pa = (float)area * (1.0f/16384.0f) * 0.057f;
            ws[PA_OFF + b] = pa;
            ws[R2ADA_OFF + b] = pa * pa;
        }
    } else {
        int b = job - 2;
        scan1024(uw, CNT_SIL + b * 1024, OFF_SIL + b * 1024, s, t);
    }
}

__device__ __forceinline__ void body_cnt_ada(float* __restrict__ ws, int p) {
    unsigned* uw = (unsigned*)ws;
    int b = p >> 14;
    float4 q = ((const float4*)(ws + PROJ1))[p];
    float pa = ws[PA_OFF + b];
    int bxl, bxh, byl, byh;
    bin_bbox(q, pa, bxl, bxh, byl, byh);
    for (int by = byl; by <= byh; by++)
        for (int bx = bxl; bx <= bxh; bx++)
            atomicAdd(&uw[CNT_ADA + b * 1024 + by * 32 + bx], 1u);
}

__device__ __forceinline__ void body_scat_sil(float* __restrict__ ws, int p) {
    unsigned* uw = (unsigned*)ws;
    int b = p >> 14;
    float4 q = ((const float4*)(ws + PROJ0))[p];
    int bxl, bxh, byl, byh;
    bin_bbox(q, R_SILF, bxl, bxh, byl, byh);
    for (int by = byl; by <= byh; by++)
        for (int bx = bxl; bx <= bxh; bx++) {
            unsigned bin = b * 1024 + by * 32 + bx;
            unsigned idx = uw[OFF_SIL + bin] + atomicAdd(&uw[CNT_SIL + bin], 1u);
            ((float4*)(ws + LSILF))[b * 65536 + idx] = q;
        }
}

__device__ __forceinline__ void body_scan_ada(float* __restrict__ ws, int b, int t) {
    unsigned* uw = (unsigned*)ws;
    unsigned c[16]; unsigned tot = 0;
    #pragma unroll
    for (int j = 0; j < 16; j++) { c[j] = uw[CNT_ADA + b * 1024 + t * 16 + j]; tot += c[j]; }
    unsigned inc = tot;
    #pragma unroll
    for (int off = 1; off < 64; off <<= 1) {
        unsigned v = __shfl_up(inc, off);
        if (t >= off) inc += v;
    }
    unsigned base = inc - tot;
    #pragma unroll
    for (int j = 0; j < 16; j++) {
        uw[OFF_ADA + b * 1024 + t * 16 + j] = base;
        base += c[j];
        uw[CNT_ADA + b * 1024 + t * 16 + j] = 0u;
    }
}

__device__ __forceinline__ void body_scat_ada(float* __restrict__ ws, int p) {
    unsigned* uw = (unsigned*)ws;
    int b = p >> 14;
    float4 q = ((const float4*)(ws + PROJ1))[p];
    float pa = ws[PA_OFF + b];
    int bxl, bxh, byl, byh;
    bin_bbox(q, pa, bxl, bxh, byl, byh);
    for (int by = byl; by <= byh; by++)
        for (int bx = bxl; bx <= bxh; bx++) {
            unsigned bin = b * 1024 + by * 32 + bx;
            unsigned idx = uw[OFF_ADA + bin] + atomicAdd(&uw[CNT_ADA + bin], 1u);
            ((float4*)(ws + LADAF))[b * 147456 + idx] = q;
        }
}

__device__ __forceinline__ void body_gather(const float* __restrict__ ws,
                                            float* __restrict__ out,
                                            int id, int lane) {
    const unsigned* uw = (const unsigned*)ws;
    bool sil = id < 2048;
    int gt = sil ? id : id - 2048;
    int b = gt >> 10;
    int tile = gt & 1023;
    int p = lane & 15, s = lane >> 4;
    int bx = tile & 31, by = tile >> 5;
    int col = (bx << 2) + (p & 3), row = (by << 2) + (p >> 2);
    float gx = 1.0f - (float)(2*col + 1) * (1.0f/128.0f);
    float gy = 1.0f - (float)(2*row + 1) * (1.0f/128.0f);
    float r2 = sil ? R2_SIL : ws[R2ADA_OFF + b];
    unsigned start = sil ? uw[OFF_SIL + b * 1024 + tile] : uw[OFF_ADA + b * 1024 + tile];
    unsigned len   = sil ? uw[CNT_SIL + b * 1024 + tile] : uw[CNT_ADA + b * 1024 + tile];
    const float4* lst = sil ? ((const float4*)(ws + LSILF)) + b * 65536 + start
                            : ((const float4*)(ws + LADAF)) + b * 147456 + start;

    float tz[8], td[8];
    #pragma unroll
    for (int k = 0; k < 8; k++) { tz[k] = INFINITY; td[k] = 0.0f; }

    unsigned i = (unsigned)s;
    while (i + 28 < len) {
        float4 cb[8];
        #pragma unroll
        for (int u = 0; u < 8; u++) cb[u] = lst[i + 4u * (unsigned)u];
        #pragma unroll
        for (int u = 0; u < 8; u++) hit_test(cb[u], gx, gy, r2, tz, td);
        i += 32;
    }
    for (; i < len; i += 4) hit_test(lst[i], gx, gy, r2, tz, td);

    merge_sorted8(tz, td, 16);
    merge_sorted8(tz, td, 32);

    if (s == 0) {
        int pix = (b << 14) + row * 128 + col;
        if (sil) {
            float trans = 1.0f, acc = 0.0f;
            #pragma unroll
            for (int k = 0; k < 8; k++) {
                float a = (tz[k] != INFINITY) ? (1.0f - td[k] / R2_SIL) : 0.0f;
                acc += a * trans;
                trans *= (1.0f - a);
            }
            out[pix] = acc * 255.0f;
        } else {
            float* dep = out + 32768  + (size_t)pix * 8;
            float* dst = out + 294912 + (size_t)pix * 8;
            #pragma unroll
            for (int k = 0; k < 8; k++) {
                bool v = (tz[k] != INFINITY);
                dep[k] = v ? tz[k] : -1.0f;
                dst[k] = v ? td[k] : -1.0f;
            }
        }
    }
}

// ============== FUSED cooperative kernel v2 (tier-0) ==============
// 4 grid.syncs; LDS-privatized histograms + two-pass scatter;
// small phases folded into last-finishing block (ticket + fences).
__global__ __launch_bounds__(256) void k_fusedp(const float* __restrict__ pc,
                                                const float* __restrict__ param,
                                                float* __restrict__ ws,
                                                float* __restrict__ out,
                                                float ue0, float ue1,
                                                float ua0, float ua1) {
    cg::grid_group grid = cg::this_grid();
    unsigned* uw = (unsigned*)ws;
    __shared__ unsigned sh[2048];      // [0..1023] hist/cursor, [1024..2047] base
    __shared__ unsigned shLast;
    int t = threadIdx.x;
    int tid = blockIdx.x * 256 + t;

    // ---- Phase A: zero [48, ZERO_END) + cameras ----
    for (int i = 48 + tid; i < ZERO_END; i += FUSED_NT) uw[i] = 0u;
    if (tid < 4) cam_compute(param, ws, tid, ue0, ue1, ua0, ua1);
    grid.sync();

    // ---- Phase B: projection (blocks 0..127), CNT_SIL privatized in LDS ----
    if (blockIdx.x < 128) {
        int b = blockIdx.x >> 6;
        int p = ((blockIdx.x & 63) << 8) + t;
        unsigned char* fb = (unsigned char*)(uw + FLAGS8);
        const float* P = pc + ((size_t)b * NPTS + p) * 6;
        float c0[12], c1[12];
        const float* w0 = ws + (b * 2) * 12;
        #pragma unroll
        for (int i = 0; i < 12; i++) { c0[i] = w0[i]; c1[i] = w0[12 + i]; }

        #pragma unroll
        for (int j = 0; j < 4; j++) sh[t * 4 + j] = 0u;
        __syncthreads();

        float4 q0 = project_pt(P, c0);
        ((float4*)(ws + PROJ0))[b * NPTS + p] = q0;
        int bxl, bxh, byl, byh;
        bin_bbox(q0, R_SILF, bxl, bxh, byl, byh);
        for (int by = byl; by <= byh; by++)
            for (int bx = bxl; bx <= bxh; bx++)
                atomicAdd(&sh[by * 32 + bx], 1u);

        float4 q1 = project_pt(P, c1);
        ((float4*)(ws + PROJ1))[b * NPTS + p] = q1;
        if (q1.z > 0.0f) {
            int cl, chh, rl, rh;
            pix_range(q1.x, R_DEPF, cl, chh);
            pix_range(q1.y, R_DEPF, rl, rh);
            for (int rr = rl; rr <= rh; rr++) {
                float gyv = 1.0f - (float)(2 * rr + 1) * (1.0f/128.0f);
                float dy = gyv - q1.y;
                for (int cc = cl; cc <= chh; cc++) {
                    float gxv = 1.0f - (float)(2 * cc + 1) * (1.0f/128.0f);
                    float dx = gxv - q1.x;
                    if (dx*dx + dy*dy < R2_DEP) fb[b * NPTS + rr * 128 + cc] = 1;
                }
            }
        }
        __syncthreads();
        #pragma unroll
        for (int j = 0; j < 4; j++) {
            unsigned c = sh[t * 4 + j];
            if (c) atomicAdd(&uw[CNT_SIL + b * 1024 + t * 4 + j], c);
        }
        __threadfence();               // release: flags + proj + counts
    }
    // ticket: last block runs area popcount + sil scan (4 jobs)
    if (t == 0) shLast = (atomicAdd(&uw[TICK0], 1u) == FUSED_BLOCKS - 1) ? 1u : 0u;
    __syncthreads();
    if (shLast) {
        __threadfence();               // acquire: invalidate stale cache
        for (int job = 0; job < 4; job++) {
            body_area_scan(ws, job, t, sh);
            __syncthreads();
        }
        __threadfence();               // release scan outputs
    }
    grid.sync();

    // ---- Phase D: cntada (blocks 0..127) + scatsil (blocks 128..255), privatized ----
    if (blockIdx.x < 128) {
        int b = blockIdx.x >> 6;
        int p = ((blockIdx.x & 63) << 8) + t;
        float4 q = ((const float4*)(ws + PROJ1))[b * NPTS + p];
        float pa = ws[PA_OFF + b];
        #pragma unroll
        for (int j = 0; j < 4; j++) sh[t * 4 + j] = 0u;
        __syncthreads();
        int bxl, bxh, byl, byh;
        bin_bbox(q, pa, bxl, bxh, byl, byh);
        for (int by = byl; by <= byh; by++)
            for (int bx = bxl; bx <= bxh; bx++)
                atomicAdd(&sh[by * 32 + bx], 1u);
        __syncthreads();
        #pragma unroll
        for (int j = 0; j < 4; j++) {
            unsigned c = sh[t * 4 + j];
            if (c) atomicAdd(&uw[CNT_ADA + b * 1024 + t * 4 + j], c);
        }
        __threadfence();
    } else if (blockIdx.x < 256) {
        int blk = blockIdx.x - 128;
        int b = blk >> 6;
        int p = ((blk & 63) << 8) + t;
        float4 q = ((const float4*)(ws + PROJ0))[b * NPTS + p];
        int bxl, bxh, byl, byh;
        bin_bbox(q, R_SILF, bxl, bxh, byl, byh);
        #pragma unroll
        for (int j = 0; j < 4; j++) sh[t * 4 + j] = 0u;
        __syncthreads();
        for (int by = byl; by <= byh; by++)
            for (int bx = bxl; bx <= bxh; bx++)
                atomicAdd(&sh[by * 32 + bx], 1u);
        __syncthreads();
        #pragma unroll
        for (int j = 0; j < 4; j++) {
            int bin = t * 4 + j;
            unsigned c = sh[bin];
            unsigned gb = 0;
            if (c) gb = uw[OFF_SIL + b * 1024 + bin] +
                        atomicAdd(&uw[CNT_SIL + b * 1024 + bin], c);
            sh[1024 + bin] = gb;
            sh[bin] = 0u;              // becomes local cursor
        }
        __syncthreads();
        for (int by = byl; by <= byh; by++)
            for (int bx = bxl; bx <= bxh; bx++) {
                int bin = by * 32 + bx;
                unsigned loc = atomicAdd(&sh[bin], 1u);
                ((float4*)(ws + LSILF))[b * 65536 + sh[1024 + bin] + loc] = q;
            }
        __threadfence();
    }
    // ticket: last block runs ada scan (2 waves)
    if (t == 0) shLast = (atomicAdd(&uw[TICK1], 1u) == FUSED_BLOCKS - 1) ? 1u : 0u;
    __syncthreads();
    if (shLast) {
        __threadfence();
        if (t < 128) body_scan_ada(ws, t >> 6, t & 63);
        __threadfence();
    }
    grid.sync();

    // ---- Phase F: scatter ada (blocks 0..127), privatized two-pass ----
    if (blockIdx.x < 128) {
        int b = blockIdx.x >> 6;
        int p = ((blockIdx.x & 63) << 8) + t;
        float4 q = ((const float4*)(ws + PROJ1))[b * NPTS + p];
        float pa = ws[PA_OFF + b];
        int bxl, bxh, byl, byh;
        bin_bbox(q, pa, bxl, bxh, byl, byh);
        #pragma unroll
        for (int j = 0; j < 4; j++) sh[t * 4 + j] = 0u;
        __syncthreads();
        for (int by = byl; by <= byh; by++)
            for (int bx = bxl; bx <= bxh; bx++)
                atomicAdd(&sh[by * 32 + bx], 1u);
        __syncthreads();
        #pragma unroll
        for (int j = 0; j < 4; j++) {
            int bin = t * 4 + j;
            unsigned c = sh[bin];
            unsigned gb = 0;
            if (c) gb = uw[OFF_ADA + b * 1024 + bin] +
                        atomicAdd(&uw[CNT_ADA + b * 1024 + bin], c);
            sh[1024 + bin] = gb;
            sh[bin] = 0u;
        }
        __syncthreads();
        for (int by = byl; by <= byh; by++)
            for (int bx = bxl; bx <= bxh; bx++) {
                int bin = by * 32 + bx;
                unsigned loc = atomicAdd(&sh[bin], 1u);
                ((float4*)(ws + LADAF))[b * 147456 + sh[1024 + bin] + loc] = q;
            }
    }
    grid.sync();

    // ---- Phase G: gather — wave (tid>>6) = tile id 0..4095 ----
    body_gather(ws, out, tid >> 6, tid & 63);
}

// ============== TIER-1 split kernels (round-6 known-good) ==============

__global__ __launch_bounds__(256) void k_zero(float* __restrict__ ws) {
    unsigned* uw = (unsigned*)ws;
    int gid = blockIdx.x * 256 + threadIdx.x;
    int stride = gridDim.x * 256;
    for (int i = 48 + gid; i < ZERO_END; i += stride) uw[i] = 0u;
}

__global__ __launch_bounds__(256) void k_proj_v3(const float* __restrict__ pc,
                                                 const float* __restrict__ param,
                                                 float* __restrict__ ws,
                                                 float ue0, float ue1,
                                                 float ua0, float ua1) {
    int b = blockIdx.x >> 6;
    int p = ((blockIdx.x & 63) << 8) + threadIdx.x;
    float azim0 = param[b * 24 + 0];
    float elev0 = param[b * 24 + 3];
    float c0[12], c1[12];
    cam_calc(elev0, azim0, c0);
    float ue = b ? ue1 : ue0;
    float ua = b ? ua1 : ua0;
    cam_calc(ue * 60.0f - 30.0f, ua * 300.0f + azim0 + 30.0f, c1);

    unsigned* uw = (unsigned*)ws;
    unsigned char* fb = (unsigned char*)(uw + FLAGS8);
    const float* P = pc + ((size_t)b * NPTS + p) * 6;

    float4 q0 = project_pt(P, c0);
    ((float4*)(ws + PROJ0))[b * NPTS + p] = q0;
    int bxl, bxh, byl, byh;
    bin_bbox(q0, R_SILF, bxl, bxh, byl, byh);
    for (int by = byl; by <= byh; by++)
        for (int bx = bxl; bx <= bxh; bx++)
            atomicAdd(&uw[CNT_SIL + b * 1024 + by * 32 + bx], 1u);

    float4 q1 = project_pt(P, c1);
    ((float4*)(ws + PROJ1))[b * NPTS + p] = q1;
    if (q1.z > 0.0f) {
        int cl, chh, rl, rh;
        pix_range(q1.x, R_DEPF, cl, chh);
        pix_range(q1.y, R_DEPF, rl, rh);
        for (int rr = rl; rr <= rh; rr++) {
            float gy = 1.0f - (float)(2 * rr + 1) * (1.0f/128.0f);
            float dy = gy - q1.y;
            for (int cc = cl; cc <= chh; cc++) {
                float gx = 1.0f - (float)(2 * cc + 1) * (1.0f/128.0f);
                float dx = gx - q1.x;
                if (dx*dx + dy*dy < R2_DEP) fb[b * NPTS + rr * 128 + cc] = 1;
            }
        }
    }
}

__global__ __launch_bounds__(256) void k_area_scan_v3(float* __restrict__ ws) {
    __shared__ unsigned s[256];
    body_area_scan(ws, blockIdx.x, threadIdx.x, s);
}

__global__ __launch_bounds__(64) void k_cntada_scatsil(float* __restrict__ ws) {
    int id = blockIdx.x;
    bool isCnt = id < 512;
    int p = ((isCnt ? id : id - 512) << 6) + threadIdx.x;
    if (isCnt) body_cnt_ada(ws, p);
    else       body_scat_sil(ws, p);
}

__global__ __launch_bounds__(64) void k_scan_ada64(float* __restrict__ ws) {
    body_scan_ada(ws, blockIdx.x, threadIdx.x);
}

__global__ __launch_bounds__(64) void k_scatter_ada_v2(float* __restrict__ ws) {
    body_scat_ada(ws, (blockIdx.x << 6) + threadIdx.x);
}

__global__ __launch_bounds__(64) void k_gather_v3(const float* __restrict__ ws,
                                                  float* __restrict__ out) {
    body_gather(ws, out, blockIdx.x, threadIdx.x);
}

// ============== TIER-2 kernels (round-2 known-good, pid lists) ==============

__global__ __launch_bounds__(256) void k_init(const float* __restrict__ param,
                                              float* __restrict__ ws,
                                              float ue0, float ue1,
                                              float ua0, float ua1) {
    unsigned* uw = (unsigned*)ws;
    int gid = blockIdx.x * 256 + threadIdx.x;
    int stride = gridDim.x * 256;
    for (int i = gid; i < 2048; i += stride) { uw[CNT_SIL + i] = 0u; uw[CNT_ADA + i] = 0u; }
    for (int i = gid; i < 32768; i += stride) uw[FLAGS + i] = 0u;
    if (gid < 2) uw[AREA_OFF + gid] = 0u;
    if (gid < 4) cam_compute(param, ws, gid, ue0, ue1, ua0, ua1);
}

__global__ __launch_bounds__(256) void k_proj_count(const float* __restrict__ pc,
                                                    float* __restrict__ ws) {
    unsigned* uw = (unsigned*)ws;
    int b = blockIdx.x >> 6;
    int p = ((blockIdx.x & 63) << 8) + threadIdx.x;
    const float* P = pc + ((size_t)b * NPTS + p) * 6;
    float c0[12], c1[12];
    const float* w0 = ws + (b * 2) * 12;
    #pragma unroll
    for (int i = 0; i < 12; i++) { c0[i] = w0[i]; c1[i] = w0[12 + i]; }

    float4 q0 = project_pt(P, c0);
    ((float4*)(ws + PROJ0))[b * NPTS + p] = q0;
    int bxl, bxh, byl, byh;
    bin_bbox(q0, R_SILF, bxl, bxh, byl, byh);
    for (int by = byl; by <= byh; by++)
        for (int bx = bxl; bx <= bxh; bx++)
            atomicAdd(&uw[CNT_SIL + b * 1024 + by * 32 + bx], 1u);

    float4 q1 = project_pt(P, c1);
    ((float4*)(ws + PROJ1))[b * NPTS + p] = q1;
    if (q1.z > 0.0f) {
        int cl, chh, rl, rh;
        pix_range(q1.x, R_DEPF, cl, chh);
        pix_range(q1.y, R_DEPF, rl, rh);
        for (int rr = rl; rr <= rh; rr++) {
            float gy = 1.0f - (float)(2 * rr + 1) * (1.0f/128.0f);
            float dy = gy - q1.y;
            for (int cc = cl; cc <= chh; cc++) {
                float gx = 1.0f - (float)(2 * cc + 1) * (1.0f/128.0f);
                float dx = gx - q1.x;
                if (dx*dx + dy*dy < R2_DEP) uw[FLAGS + b * NPTS + rr * 128 + cc] = 1u;
            }
        }
    }
}

__global__ __launch_bounds__(256) void k_area_scan(float* __restrict__ ws) {
    unsigned* uw = (unsigned*)ws;
    __shared__ unsigned s[256];
    int t = threadIdx.x;
    int job = blockIdx.x;
    if (job < 2) {
        int b = job;
        unsigned acc = 0;
        for (int i = t; i < NPTS; i += 256) acc += uw[FLAGS + b * NPTS + i];
        s[t] = acc; __syncthreads();
        for (int off = 128; off > 0; off >>= 1) {
            if (t < off) s[t] += s[t + off];
            __syncthreads();
        }
        if (t == 0) {
            unsigned area = s[0];
            uw[AREA_OFF + b] = area;
            float pa = (float)area * (1.0f/16384.0f) * 0.057f;
            ws[PA_OFF + b] = pa;
            ws[R2ADA_OFF + b] = pa * pa;
        }
    } else {
        int b = job - 2;
        scan1024(uw, CNT_SIL + b * 1024, OFF_SIL + b * 1024, s, t);
    }
}

__global__ __launch_bounds__(256) void k_count_ada(float* __restrict__ ws) {
    int b = blockIdx.x >> 6;
    int p = ((blockIdx.x & 63) << 8) + threadIdx.x;
    body_cnt_ada(ws, b * NPTS + p);
}

__global__ __launch_bounds__(256) void k_scan_ada(float* __restrict__ ws) {
    unsigned* uw = (unsigned*)ws;
    __shared__ unsigned s[256];
    int b = blockIdx.x;
    scan1024(uw, CNT_ADA + b * 1024, OFF_ADA + b * 1024, s, threadIdx.x);
}

__global__ __launch_bounds__(256) void k_scatter(float* __restrict__ ws) {
    unsigned* uw = (unsigned*)ws;
    int b = blockIdx.x >> 6;
    int p = ((blockIdx.x & 63) << 8) + threadIdx.x;

    float4 q0 = ((const float4*)(ws + PROJ0))[b * NPTS + p];
    int bxl, bxh, byl, byh;
    bin_bbox(q0, R_SILF, bxl, bxh, byl, byh);
    for (int by = byl; by <= byh; by++)
        for (int bx = bxl; bx <= bxh; bx++) {
            unsigned bin = b * 1024 + by * 32 + bx;
            unsigned idx = uw[OFF_SIL + bin] + atomicAdd(&uw[CNT_SIL + bin], 1u);
            uw[LSIL + b * 65536 + idx] = (unsigned)p;
        }

    float4 q1 = ((const float4*)(ws + PROJ1))[b * NPTS + p];
    float pa = ws[PA_OFF + b];
    bin_bbox(q1, pa, bxl, bxh, byl, byh);
    for (int by = byl; by <= byh; by++)
        for (int bx = bxl; bx <= bxh; bx++) {
            unsigned bin = b * 1024 + by * 32 + bx;
            unsigned idx = uw[OFF_ADA + bin] + atomicAdd(&uw[CNT_ADA + bin], 1u);
            uw[LADA + b * 147456 + idx] = (unsigned)p;
        }
}

__global__ __launch_bounds__(256) void k_gather_sil(const float* __restrict__ ws,
                                                    float* __restrict__ out) {
    const unsigned* uw = (const unsigned*)ws;
    int b = blockIdx.x >> 6;
    int tile = (blockIdx.x & 63) * 16 + (threadIdx.x >> 4);
    int q = threadIdx.x & 15;
    int bx = tile & 31, by = tile >> 5;
    int col = (bx << 2) + (q & 3), row = (by << 2) + (q >> 2);
    float gx = 1.0f - (float)(2*col + 1) * (1.0f/128.0f);
    float gy = 1.0f - (float)(2*row + 1) * (1.0f/128.0f);
    unsigned start = uw[OFF_SIL + b * 1024 + tile];
    unsigned len   = uw[CNT_SIL + b * 1024 + tile];
    const float4* pr = (const float4*)(ws + PROJ0) + b * NPTS;

    float tz[8], td[8];
    #pragma unroll
    for (int k = 0; k < 8; k++) { tz[k] = INFINITY; td[k] = 0.0f; }
    for (unsigned i = 0; i < len; i++) {
        unsigned pid = uw[LSIL + b * 65536 + start + i];
        hit_test(pr[pid], gx, gy, R2_SIL, tz, td);
    }
    float trans = 1.0f, s = 0.0f;
    #pragma unroll
    for (int k = 0; k < 8; k++) {
        float a = (tz[k] != INFINITY) ? (1.0f - td[k] / R2_SIL) : 0.0f;
        s += a * trans;
        trans *= (1.0f - a);
    }
    out[(b << 14) + row * 128 + col] = s * 255.0f;
}

__global__ __launch_bounds__(256) void k_gather_ada(const float* __restrict__ ws,
                                                    float* __restrict__ out) {
    const unsigned* uw = (const unsigned*)ws;
    int b = blockIdx.x >> 6;
    int tile = (blockIdx.x & 63) * 16 + (threadIdx.x >> 4);
    int q = threadIdx.x & 15;
    int bx = tile & 31, by = tile >> 5;
    int col = (bx << 2) + (q & 3), row = (by << 2) + (q >> 2);
    float gx = 1.0f - (float)(2*col + 1) * (1.0f/128.0f);
    float gy = 1.0f - (float)(2*row + 1) * (1.0f/128.0f);
    float r2 = ws[R2ADA_OFF + b];
    unsigned start = uw[OFF_ADA + b * 1024 + tile];
    unsigned len   = uw[CNT_ADA + b * 1024 + tile];
    const float4* pr = (const float4*)(ws + PROJ1) + b * NPTS;

    float tz[8], td[8];
    #pragma unroll
    for (int k = 0; k < 8; k++) { tz[k] = INFINITY; td[k] = 0.0f; }
    for (unsigned i = 0; i < len; i++) {
        unsigned pid = uw[LADA + b * 147456 + start + i];
        hit_test(pr[pid], gx, gy, r2, tz, td);
    }
    int pix = (b << 14) + row * 128 + col;
    float* dep = out + 32768  + (size_t)pix * 8;
    float* dst = out + 294912 + (size_t)pix * 8;
    #pragma unroll
    for (int k = 0; k < 8; k++) {
        bool v = (tz[k] != INFINITY);
        dep[k] = v ? tz[k] : -1.0f;
        dst[k] = v ? td[k] : -1.0f;
    }
}

// ================= tier-3 brute-force (round-1 known-good) =================
__global__ void cam_kernel_fb(const float* __restrict__ param, float* __restrict__ ws,
                              float ue0, float ue1, float ua0, float ua1) {
    int t = threadIdx.x;
    if (t < 2) ws[48 + t] = 0.0f;
    if (t >= 4) return;
    cam_compute(param, ws, t, ue0, ue1, ua0, ua1);
}

__device__ __forceinline__ void stage_points(const float* __restrict__ pcb,
                                             const float c[12], int c0, float4* sp) {
    for (int i = threadIdx.x; i < CH; i += 256) {
        const float* P = pcb + (size_t)(c0 + i) * 6;
        sp[i] = project_pt(P, c);
    }
}

__global__ __launch_bounds__(256) void raster_AB(const float* __restrict__ pc,
                                                 float* __restrict__ ws,
                                                 float* __restrict__ out) {
    __shared__ float4 sp[CH];
    int bid = blockIdx.x;
    bool silMode = bid < 128;
    int q = silMode ? bid : bid - 128;
    int b = q >> 6;
    int p = ((q & 63) << 8) + threadIdx.x;
    const float* cw = ws + (b * 2 + (silMode ? 0 : 1)) * 12;
    float c[12];
    #pragma unroll
    for (int i = 0; i < 12; i++) c[i] = cw[i];
    float r2 = silMode ? R2_SIL : R2_DEP;
    int col = p & 127, row = p >> 7;
    float gx = 1.0f - (float)(2*col + 1) * (1.0f/128.0f);
    float gy = 1.0f - (float)(2*row + 1) * (1.0f/128.0f);
    const float* pcb = pc + (size_t)b * NPTS * 6;

    if (silMode) {
        float tz[8], td[8];
        #pragma unroll
        for (int k = 0; k < 8; k++) { tz[k] = INFINITY; td[k] = 0.0f; }
        for (int c0 = 0; c0 < NPTS; c0 += CH) {
            __syncthreads();
            stage_points(pcb, c, c0, sp);
            __syncthreads();
            #pragma unroll 4
            for (int j = 0; j < CH; j++) hit_test(sp[j], gx, gy, r2, tz, td);
        }
        float trans = 1.0f, s = 0.0f;
        #pragma unroll
        for (int k = 0; k < 8; k++) {
            float a = (tz[k] != INFINITY) ? (1.0f - td[k] / r2) : 0.0f;
            s += a * trans;
            trans *= (1.0f - a);
        }
        out[(b << 14) + p] = s * 255.0f;
    } else {
        float mz = INFINITY;
        for (int c0 = 0; c0 < NPTS; c0 += CH) {
            __syncthreads();
            stage_points(pcb, c, c0, sp);
            __syncthreads();
            #pragma unroll 4
            for (int j = 0; j < CH; j++) {
                float4 pt = sp[j];
                float dx = gx - pt.x, dy = gy - pt.y;
                float d2 = dx*dx + dy*dy;
                if (d2 < r2 && pt.z > 0.0f) mz = fminf(mz, pt.z);
            }
        }
        unsigned long long m = __ballot(mz != INFINITY);
        if ((threadIdx.x & 63) == 0)
            atomicAdd(ws + 48 + b, (float)__popcll(m));
    }
}

__global__ __launch_bounds__(256) void raster_C(const float* __restrict__ pc,
                                                const float* __restrict__ ws,
                                                float* __restrict__ out) {
    __shared__ float4 sp[CH];
    int bid = blockIdx.x;
    int b = bid >> 6;
    int p = ((bid & 63) << 8) + threadIdx.x;
    const float* cw = ws + (b * 2 + 1) * 12;
    float c[12];
    #pragma unroll
    for (int i = 0; i < 12; i++) c[i] = cw[i];
    float area = ws[48 + b];
    float pa = (area * (1.0f/16384.0f)) * 0.057f;
    float r2 = pa * pa;
    int col = p & 127, row = p >> 7;
    float gx = 1.0f - (float)(2*col + 1) * (1.0f/128.0f);
    float gy = 1.0f - (float)(2*row + 1) * (1.0f/128.0f);
    const float* pcb = pc + (size_t)b * NPTS * 6;

    float tz[8], td[8];
    #pragma unroll
    for (int k = 0; k < 8; k++) { tz[k] = INFINITY; td[k] = 0.0f; }
    for (int c0 = 0; c0 < NPTS; c0 += CH) {
        __syncthreads();
        stage_points(pcb, c, c0, sp);
        __syncthreads();
        #pragma unroll 4
        for (int j = 0; j < CH; j++) hit_test(sp[j], gx, gy, r2, tz, td);
    }
    float* dep = out + 32768  + (size_t)((b << 14) + p) * 8;
    float* dst = out + 294912 + (size_t)((b << 14) + p) * 8;
    #pragma unroll
    for (int k = 0; k < 8; k++) {
        bool v = (tz[k] != INFINITY);
        dep[k] = v ? tz[k] : -1.0f;
        dst[k] = v ? td[k] : -1.0f;
    }
}

// ---------------- host-side threefry2x32-20 (JAX-compatible) ----------------
static inline uint32_t rotl32(uint32_t x, int r) { return (x << r) | (x >> (32 - r)); }

static void tf2x32(uint32_t k0, uint32_t k1, uint32_t c0, uint32_t c1,
                   uint32_t* o0, uint32_t* o1) {
    uint32_t ks0 = k0, ks1 = k1, ks2 = k0 ^ k1 ^ 0x1BD11BDAu;
    uint32_t x0 = c0 + ks0, x1 = c1 + ks1;
    static const int rA[4] = {13, 15, 26, 6};
    static const int rB[4] = {17, 29, 16, 24};
    #define RND4(R) do { for (int i = 0; i < 4; i++) { x0 += x1; x1 = rotl32(x1, R[i]); x1 ^= x0; } } while (0)
    RND4(rA); x0 += ks1; x1 += ks2 + 1u;
    RND4(rB); x0 += ks2; x1 += ks0 + 2u;
    RND4(rA); x0 += ks0; x1 += ks1 + 3u;
    RND4(rB); x0 += ks1; x1 += ks2 + 4u;
    RND4(rA); x0 += ks2; x1 += ks0 + 5u;
    #undef RND4
    *o0 = x0; *o1 = x1;
}

static inline float bits_to_unit_float(uint32_t bits) {
    uint32_t fb = (bits >> 9) | 0x3f800000u;
    float f;
    memcpy(&f, &fb, 4);
    return f - 1.0f;
}

extern "C" void kernel_launch(void* const* d_in, const int* in_sizes, int n_in,
                              void* d_out, int out_size, void* d_ws, size_t ws_size,
                              hipStream_t stream) {
    const float* pc    = (const float*)d_in[0];
    const float* param = (const float*)d_in[1];
    float* out = (float*)d_out;
    float* ws  = (float*)d_ws;

    uint32_t ke0, ke1, ka0, ka1, b1, b2;
    tf2x32(0u, 42u, 0u, 0u, &ke0, &ke1);
    tf2x32(0u, 42u, 0u, 1u, &ka0, &ka1);
    float ue[2], ua[2];
    for (uint32_t i = 0; i < 2; i++) {
        tf2x32(ke0, ke1, 0u, i, &b1, &b2);
        ue[i] = bits_to_unit_float(b1 ^ b2);
        tf2x32(ka0, ka1, 0u, i, &b1, &b2);
        ua[i] = bits_to_unit_float(b1 ^ b2);
    }
    float ue0 = ue[0], ue1 = ue[1], ua0 = ua[0], ua1 = ua[1];

    if (ws_size >= WS1_NEEDED) {
        int dev = 0;
        hipGetDevice(&dev);
        hipDeviceProp_t prop;
        bool coop = (hipGetDeviceProperties(&prop, dev) == hipSuccess) &&
                    prop.cooperativeLaunch;
        if (coop) {
            int maxB = 0;
            if (hipOccupancyMaxActiveBlocksPerMultiprocessor(&maxB, k_fusedp, 256, 0)
                    != hipSuccess ||
                maxB * prop.multiProcessorCount < FUSED_BLOCKS)
                coop = false;
        }
        if (coop) {
            void* args[] = { (void*)&pc, (void*)&param, (void*)&ws, (void*)&out,
                             (void*)&ue0, (void*)&ue1, (void*)&ua0, (void*)&ua1 };
            hipError_t e = hipLaunchCooperativeKernel((const void*)k_fusedp,
                                                      dim3(FUSED_BLOCKS), dim3(256),
                                                      args, 0, stream);
            if (e == hipSuccess) return;
        }
        // tier-1 split path (round-6 known-good)
        k_zero          <<<16, 256, 0, stream>>>(ws);
        k_proj_v3       <<<128, 256, 0, stream>>>(pc, param, ws, ue0, ue1, ua0, ua1);
        k_area_scan_v3  <<<4, 256, 0, stream>>>(ws);
        k_cntada_scatsil<<<1024, 64, 0, stream>>>(ws);
        k_scan_ada64    <<<2, 64, 0, stream>>>(ws);
        k_scatter_ada_v2<<<512, 64, 0, stream>>>(ws);
        k_gather_v3     <<<4096, 64, 0, stream>>>(ws, out);
    } else if (ws_size >= WS2_NEEDED) {
        k_init      <<<64, 256, 0, stream>>>(param, ws, ue0, ue1, ua0, ua1);
        k_proj_count<<<128, 256, 0, stream>>>(pc, ws);
        k_area_scan <<<4, 256, 0, stream>>>(ws);
        k_count_ada <<<128, 256, 0, stream>>>(ws);
        k_scan_ada  <<<2, 256, 0, stream>>>(ws);
        k_scatter   <<<128, 256, 0, stream>>>(ws);
        k_gather_sil<<<128, 256, 0, stream>>>(ws, out);
        k_gather_ada<<<128, 256, 0, stream>>>(ws, out);
    } else {
        cam_kernel_fb<<<1, 64, 0, stream>>>(param, ws, ue0, ue1, ua0, ua1);
        raster_AB<<<256, 256, 0, stream>>>(pc, ws, out);
        raster_C <<<128, 256, 0, stream>>>(pc, ws, out);
    }
}

// Round 9
// 85.718 us; speedup vs baseline: 1.0794x; 1.0794x over previous
//
#include <hip/hip_runtime.h>
#include <hip/hip_cooperative_groups.h>
#include <cstring>
#include <cstdint>

namespace cg = cooperative_groups;

#define NPTS 16384
#define FUVC 140.0f
#define R_SILF 0.008f
#define R_DEPF 0.012f
#define R2_SIL (0.008f*0.008f)
#define R2_DEP (0.012f*0.012f)
#define CH 512

// ---------------- ws layout (32-bit word offsets) ----------------
#define AREA_OFF  48
#define PA_OFF    50
#define R2ADA_OFF 52
#define TICK0     54
#define TICK1     55
#define CNT_SIL   64
#define OFF_SIL   2112
#define CNT_ADA   4160
#define OFF_ADA   6208
#define FLAGS8    8256   // tier-0/1: u8[2][16384] per-pixel any-hit (plain byte stores)
#define FLAGS     8256   // tier-2: u32[2][16384] (legacy layout, disjoint use)
#define ZERO_END  16448  // zero region = words [48, ZERO_END)
#define PROJ0     41024
#define PROJ1     172096
#define LSILF     303168                 // float4[2][65536]
#define LADAF     827456                 // float4[2][147456]
#define WS1_WORDS 2007104u
#define WS1_NEEDED ((size_t)WS1_WORDS * 4u)
#define LSIL      303168
#define LADA      434240
#define WS2_WORDS 729152u
#define WS2_NEEDED ((size_t)WS2_WORDS * 4u)

#define FUSED_BLOCKS 1024
#define FUSED_NT (FUSED_BLOCKS * 256)

// ---------------- shared device helpers ----------------
__device__ __forceinline__ void cam_calc(float elev, float azim, float c[12]) {
    const float D2R = 0.017453292519943295f;
    float er = elev * D2R, ar = azim * D2R;
    float ce = cosf(er), se = sinf(er), ca = cosf(ar), sa = sinf(ar);
    float cx = 1.2f * ce * sa, cy = 1.2f * se, cz = 1.2f * ce * ca;
    float n = sqrtf(cx*cx + cy*cy + cz*cz) + 1e-8f;
    float zx = -cx / n, zy = -cy / n, zz = -cz / n;
    float xx = zz, xy = 0.0f, xz = -zx;
    float xn = sqrtf(xx*xx + xy*xy + xz*xz) + 1e-8f;
    xx /= xn; xz /= xn;
    float yx = zy*xz - zz*xy, yy = zz*xx - zx*xz, yz = zx*xy - zy*xx;
    c[0]=xx; c[1]=xy; c[2]=xz; c[3]=yx; c[4]=yy; c[5]=yz;
    c[6]=zx; c[7]=zy; c[8]=zz;
    c[9]  = -(cx*xx + cy*xy + cz*xz);
    c[10] = -(cx*yx + cy*yy + cz*yz);
    c[11] = -(cx*zx + cy*zy + cz*zz);
}

__device__ __forceinline__ void cam_compute(const float* __restrict__ param,
                                            float* __restrict__ ws,
                                            int t, float ue0, float ue1,
                                            float ua0, float ua1) {
    int b = t >> 1, cam = t & 1;
    float azim0 = param[b * 24 + 0];
    float elev0 = param[b * 24 + 3];
    float elev, azim;
    if (cam == 0) { elev = elev0; azim = azim0; }
    else {
        float ue = b ? ue1 : ue0;
        float ua = b ? ua1 : ua0;
        elev = ue * 60.0f - 30.0f;
        azim = ua * 300.0f + azim0 + 30.0f;
    }
    float c[12];
    cam_calc(elev, azim, c);
    float* w = ws + t * 12;
    #pragma unroll
    for (int i = 0; i < 12; i++) w[i] = c[i];
}

__device__ __forceinline__ float4 project_pt(const float* __restrict__ P,
                                             const float c[12]) {
    float X = P[0], Y = P[1], Z = P[2];
    float xc = X*c[0] + Y*c[1] + Z*c[2] + c[9];
    float yc = X*c[3] + Y*c[4] + Z*c[5] + c[10];
    float zc = X*c[6] + Y*c[7] + Z*c[8] + c[11];
    float zs = zc > 1e-5f ? zc : 1.0f;
    float px = 1.0f - (FUVC * xc / zs + 64.0f) * (1.0f/64.0f);
    float py = 1.0f - (FUVC * yc / zs + 64.0f) * (1.0f/64.0f);
    return make_float4(px, py, zc, 0.0f);
}

__device__ __forceinline__ void pix_range(float p, float r, int& lo, int& hi) {
    float lo_f = (1.0f - p - r) * 64.0f - 0.5f;
    float hi_f = (1.0f - p + r) * 64.0f - 0.5f;
    lo = (int)ceilf(lo_f - 1e-3f);
    hi = (int)floorf(hi_f + 1e-3f);
    lo = max(lo, 0); hi = min(hi, 127);
}

// bbox in 4x4-pixel bin coords; empty -> byh < byl
__device__ __forceinline__ void bin_bbox(float4 q, float r, int& bxl, int& bxh,
                                         int& byl, int& byh) {
    bxl = 0; bxh = -1; byl = 0; byh = -1;
    if (q.z > 0.0f) {
        int cl, chh, rl, rh;
        pix_range(q.x, r, cl, chh);
        pix_range(q.y, r, rl, rh);
        if (cl <= chh && rl <= rh) {
            bxl = cl >> 2; bxh = chh >> 2; byl = rl >> 2; byh = rh >> 2;
        }
    }
}

__device__ __forceinline__ void top8_insert(float z, float d,
                                            float tz[8], float td[8]) {
    #pragma unroll
    for (int k = 0; k < 8; k++) {
        bool lt = z < tz[k];
        float oz = tz[k], od = td[k];
        if (lt) { tz[k] = z; td[k] = d; z = oz; d = od; }
    }
}

__device__ __forceinline__ void hit_test(float4 pt, float gx, float gy, float r2,
                                         float tz[8], float td[8]) {
    float dx = gx - pt.x, dy = gy - pt.y;
    float d2 = dx*dx + dy*dy;
    if (d2 < r2 && pt.z > 0.0f && pt.z < tz[7]) top8_insert(pt.z, d2, tz, td);
}

#define CE8(i, j) { bool sw = mz[j] < mz[i]; \
    float t1 = mz[i], t2 = md[i]; \
    mz[i] = sw ? mz[j] : mz[i]; md[i] = sw ? md[j] : md[i]; \
    mz[j] = sw ? t1 : mz[j];    md[j] = sw ? t2 : md[j]; }

// merge partner's sorted top-8 (via shfl_xor) into ours: bitonic lower-half + sort
__device__ __forceinline__ void merge_sorted8(float tz[8], float td[8], int mask) {
    float oz[8], od[8];
    #pragma unroll
    for (int k = 0; k < 8; k++) {
        oz[k] = __shfl_xor(tz[k], mask);
        od[k] = __shfl_xor(td[k], mask);
    }
    float mz[8], md[8];
    #pragma unroll
    for (int k = 0; k < 8; k++) {
        bool take = oz[7 - k] < tz[k];
        mz[k] = take ? oz[7 - k] : tz[k];
        md[k] = take ? od[7 - k] : td[k];
    }
    CE8(0,4) CE8(1,5) CE8(2,6) CE8(3,7)
    CE8(0,2) CE8(1,3) CE8(4,6) CE8(5,7)
    CE8(0,1) CE8(2,3) CE8(4,5) CE8(6,7)
    #pragma unroll
    for (int k = 0; k < 8; k++) { tz[k] = mz[k]; td[k] = md[k]; }
}

// merge a sorted top-8 read from memory into ours (same network, no shfl)
__device__ __forceinline__ void merge_seq8(float tz[8], float td[8],
                                           const float* __restrict__ ozp,
                                           const float* __restrict__ odp) {
    float mz[8], md[8];
    #pragma unroll
    for (int k = 0; k < 8; k++) {
        float oz = ozp[7 - k], od = odp[7 - k];
        bool take = oz < tz[k];
        mz[k] = take ? oz : tz[k];
        md[k] = take ? od : td[k];
    }
    CE8(0,4) CE8(1,5) CE8(2,6) CE8(3,7)
    CE8(0,2) CE8(1,3) CE8(4,6) CE8(5,7)
    CE8(0,1) CE8(2,3) CE8(4,5) CE8(6,7)
    #pragma unroll
    for (int k = 0; k < 8; k++) { tz[k] = mz[k]; td[k] = md[k]; }
}

__device__ __forceinline__ void scan1024(unsigned* uw, unsigned cbase,
                                         unsigned obase, unsigned* s, int t) {
    unsigned c0 = uw[cbase + t*4 + 0];
    unsigned c1 = uw[cbase + t*4 + 1];
    unsigned c2 = uw[cbase + t*4 + 2];
    unsigned c3 = uw[cbase + t*4 + 3];
    unsigned tot = c0 + c1 + c2 + c3;
    s[t] = tot; __syncthreads();
    for (int off = 1; off < 256; off <<= 1) {
        unsigned v = (t >= off) ? s[t - off] : 0u;
        __syncthreads();
        s[t] += v;
        __syncthreads();
    }
    unsigned base = s[t] - tot;
    uw[obase + t*4 + 0] = base;
    uw[obase + t*4 + 1] = base + c0;
    uw[obase + t*4 + 2] = base + c0 + c1;
    uw[obase + t*4 + 3] = base + c0 + c1 + c2;
    uw[cbase + t*4 + 0] = 0;
    uw[cbase + t*4 + 1] = 0;
    uw[cbase + t*4 + 2] = 0;
    uw[cbase + t*4 + 3] = 0;
}

// ---------------- device sub-bodies ----------------
__device__ __forceinline__ void body_area_scan(float* __restrict__ ws, int job,
                                               int t, unsigned* s) {
    unsigned* uw = (unsigned*)ws;
    if (job < 2) {
        int b = job;
        unsigned acc = 0;
        #pragma unroll
        for (int j = 0; j < 16; j++) {
            unsigned w = uw[FLAGS8 + b * 4096 + t * 16 + j];
            acc += __popc(w & 0x01010101u);
        }
        s[t] = acc; __syncthreads();
        for (int off = 128; off > 0; off >>= 1) {
            if (t < off) s[t] += s[t + off];
            __syncthreads();
        }
        if (t == 0) {
            unsigned area = s[0];
            uw[AREA_OFF + b] = area;
            float pa = (float)area * (1.0f/16384.0f) * 0.057f;
            ws[PA_OFF + b] = pa;
            ws[R2ADA_OFF + b] = pa * pa;
        }
    } else {
        int b = job - 2;
        scan1024(uw, CNT_SIL + b * 1024, OFF_SIL + b * 1024, s, t);
    }
}

__device__ __forceinline__ void body_cnt_ada(float* __restrict__ ws, int p) {
    unsigned* uw = (unsigned*)ws;
    int b = p >> 14;
    float4 q = ((const float4*)(ws + PROJ1))[p];
    float pa = ws[PA_OFF + b];
    int bxl, bxh, byl, byh;
    bin_bbox(q, pa, bxl, bxh, byl, byh);
    for (int by = byl; by <= byh; by++)
        for (int bx = bxl; bx <= bxh; bx++)
            atomicAdd(&uw[CNT_ADA + b * 1024 + by * 32 + bx], 1u);
}

__device__ __forceinline__ void body_scat_sil(float* __restrict__ ws, int p) {
    unsigned* uw = (unsigned*)ws;
    int b = p >> 14;
    float4 q = ((const float4*)(ws + PROJ0))[p];
    int bxl, bxh, byl, byh;
    bin_bbox(q, R_SILF, bxl, bxh, byl, byh);
    for (int by = byl; by <= byh; by++)
        for (int bx = bxl; bx <= bxh; bx++) {
            unsigned bin = b * 1024 + by * 32 + bx;
            unsigned idx = uw[OFF_SIL + bin] + atomicAdd(&uw[CNT_SIL + bin], 1u);
            ((float4*)(ws + LSILF))[b * 65536 + idx] = q;
        }
}

__device__ __forceinline__ void body_scan_ada(float* __restrict__ ws, int b, int t) {
    unsigned* uw = (unsigned*)ws;
    unsigned c[16]; unsigned tot = 0;
    #pragma unroll
    for (int j = 0; j < 16; j++) { c[j] = uw[CNT_ADA + b * 1024 + t * 16 + j]; tot += c[j]; }
    unsigned inc = tot;
    #pragma unroll
    for (int off = 1; off < 64; off <<= 1) {
        unsigned v = __shfl_up(inc, off);
        if (t >= off) inc += v;
    }
    unsigned base = inc - tot;
    #pragma unroll
    for (int j = 0; j < 16; j++) {
        uw[OFF_ADA + b * 1024 + t * 16 + j] = base;
        base += c[j];
        uw[CNT_ADA + b * 1024 + t * 16 + j] = 0u;
    }
}

__device__ __forceinline__ void body_scat_ada(float* __restrict__ ws, int p) {
    unsigned* uw = (unsigned*)ws;
    int b = p >> 14;
    float4 q = ((const float4*)(ws + PROJ1))[p];
    float pa = ws[PA_OFF + b];
    int bxl, bxh, byl, byh;
    bin_bbox(q, pa, bxl, bxh, byl, byh);
    for (int by = byl; by <= byh; by++)
        for (int bx = bxl; bx <= bxh; bx++) {
            unsigned bin = b * 1024 + by * 32 + bx;
            unsigned idx = uw[OFF_ADA + bin] + atomicAdd(&uw[CNT_ADA + bin], 1u);
            ((float4*)(ws + LADAF))[b * 147456 + idx] = q;
        }
}

// gather v4: one 256-thread block per tile; 16 list-segments x 16 px;
// in-wave butterfly (4 segs) + LDS cross-wave merge. sm = 1024 floats.
__device__ __forceinline__ void body_gather256(const float* __restrict__ ws,
                                               float* __restrict__ out,
                                               int id, int t,
                                               float* __restrict__ sm) {
    const unsigned* uw = (const unsigned*)ws;
    bool sil = id < 2048;
    int gt = sil ? id : id - 2048;
    int b = gt >> 10;
    int tile = gt & 1023;
    int p = t & 15, seg = t >> 4;          // 16 segments
    int bx = tile & 31, by = tile >> 5;
    int col = (bx << 2) + (p & 3), row = (by << 2) + (p >> 2);
    float gx = 1.0f - (float)(2*col + 1) * (1.0f/128.0f);
    float gy = 1.0f - (float)(2*row + 1) * (1.0f/128.0f);
    float r2 = sil ? R2_SIL : ws[R2ADA_OFF + b];
    unsigned start = sil ? uw[OFF_SIL + b * 1024 + tile] : uw[OFF_ADA + b * 1024 + tile];
    unsigned len   = sil ? uw[CNT_SIL + b * 1024 + tile] : uw[CNT_ADA + b * 1024 + tile];
    const float4* lst = sil ? ((const float4*)(ws + LSILF)) + b * 65536 + start
                            : ((const float4*)(ws + LADAF)) + b * 147456 + start;

    float tz[8], td[8];
    #pragma unroll
    for (int k = 0; k < 8; k++) { tz[k] = INFINITY; td[k] = 0.0f; }

    // segment `seg` handles elements seg, seg+16, seg+32, ...
    unsigned i = (unsigned)seg;
    while (i + 112 < len) {
        float4 cb[8];
        #pragma unroll
        for (int u = 0; u < 8; u++) cb[u] = lst[i + 16u * (unsigned)u];
        #pragma unroll
        for (int u = 0; u < 8; u++) hit_test(cb[u], gx, gy, r2, tz, td);
        i += 128;
    }
    for (; i < len; i += 16) hit_test(lst[i], gx, gy, r2, tz, td);

    // in-wave: merge the wave's 4 segments (lanes p, p+16, p+32, p+48)
    merge_sorted8(tz, td, 16);
    merge_sorted8(tz, td, 32);

    // cross-wave: each wave's lane p writes its merged list; wave 0 combines
    int w = t >> 6;
    if ((t & 63) < 16) {
        float* dst = sm + (w * 16 + p) * 16;
        #pragma unroll
        for (int k = 0; k < 8; k++) { dst[k] = tz[k]; dst[8 + k] = td[k]; }
    }
    __syncthreads();
    if (t < 16) {
        #pragma unroll
        for (int ww = 1; ww < 4; ww++) {
            const float* src = sm + (ww * 16 + p) * 16;
            merge_seq8(tz, td, src, src + 8);
        }
        int pix = (b << 14) + row * 128 + col;
        if (sil) {
            float trans = 1.0f, acc = 0.0f;
            #pragma unroll
            for (int k = 0; k < 8; k++) {
                float a = (tz[k] != INFINITY) ? (1.0f - td[k] / R2_SIL) : 0.0f;
                acc += a * trans;
                trans *= (1.0f - a);
            }
            out[pix] = acc * 255.0f;
        } else {
            float* dep = out + 32768  + (size_t)pix * 8;
            float* dst = out + 294912 + (size_t)pix * 8;
            #pragma unroll
            for (int k = 0; k < 8; k++) {
                bool v = (tz[k] != INFINITY);
                dep[k] = v ? tz[k] : -1.0f;
                dst[k] = v ? td[k] : -1.0f;
            }
        }
    }
}

// legacy 64-thread gather (tier-2 reference path helpers keep using hit_test)
__device__ __forceinline__ void body_gather(const float* __restrict__ ws,
                                            float* __restrict__ out,
                                            int id, int lane) {
    const unsigned* uw = (const unsigned*)ws;
    bool sil = id < 2048;
    int gt = sil ? id : id - 2048;
    int b = gt >> 10;
    int tile = gt & 1023;
    int p = lane & 15, s = lane >> 4;
    int bx = tile & 31, by = tile >> 5;
    int col = (bx << 2) + (p & 3), row = (by << 2) + (p >> 2);
    float gx = 1.0f - (float)(2*col + 1) * (1.0f/128.0f);
    float gy = 1.0f - (float)(2*row + 1) * (1.0f/128.0f);
    float r2 = sil ? R2_SIL : ws[R2ADA_OFF + b];
    unsigned start = sil ? uw[OFF_SIL + b * 1024 + tile] : uw[OFF_ADA + b * 1024 + tile];
    unsigned len   = sil ? uw[CNT_SIL + b * 1024 + tile] : uw[CNT_ADA + b * 1024 + tile];
    const float4* lst = sil ? ((const float4*)(ws + LSILF)) + b * 65536 + start
                            : ((const float4*)(ws + LADAF)) + b * 147456 + start;

    float tz[8], td[8];
    #pragma unroll
    for (int k = 0; k < 8; k++) { tz[k] = INFINITY; td[k] = 0.0f; }

    unsigned i = (unsigned)s;
    while (i + 28 < len) {
        float4 cb[8];
        #pragma unroll
        for (int u = 0; u < 8; u++) cb[u] = lst[i + 4u * (unsigned)u];
        #pragma unroll
        for (int u = 0; u < 8; u++) hit_test(cb[u], gx, gy, r2, tz, td);
        i += 32;
    }
    for (; i < len; i += 4) hit_test(lst[i], gx, gy, r2, tz, td);

    merge_sorted8(tz, td, 16);
    merge_sorted8(tz, td, 32);

    if (s == 0) {
        int pix = (b << 14) + row * 128 + col;
        if (sil) {
            float trans = 1.0f, acc = 0.0f;
            #pragma unroll
            for (int k = 0; k < 8; k++) {
                float a = (tz[k] != INFINITY) ? (1.0f - td[k] / R2_SIL) : 0.0f;
                acc += a * trans;
                trans *= (1.0f - a);
            }
            out[pix] = acc * 255.0f;
        } else {
            float* dep = out + 32768  + (size_t)pix * 8;
            float* dst = out + 294912 + (size_t)pix * 8;
            #pragma unroll
            for (int k = 0; k < 8; k++) {
                bool v = (tz[k] != INFINITY);
                dep[k] = v ? tz[k] : -1.0f;
                dst[k] = v ? td[k] : -1.0f;
            }
        }
    }
}

// ============== FUSED cooperative kernel (tier-0, R8 + gather v4) ==============
__global__ __launch_bounds__(256) void k_fusedp(const float* __restrict__ pc,
                                                const float* __restrict__ param,
                                                float* __restrict__ ws,
                                                float* __restrict__ out,
                                                float ue0, float ue1,
                                                float ua0, float ua1) {
    cg::grid_group grid = cg::this_grid();
    unsigned* uw = (unsigned*)ws;
    __shared__ unsigned sh[2048];      // hist/cursor + base; reused as merge LDS
    __shared__ unsigned shLast;
    int t = threadIdx.x;
    int tid = blockIdx.x * 256 + t;

    // ---- Phase A: zero [48, ZERO_END) + cameras ----
    for (int i = 48 + tid; i < ZERO_END; i += FUSED_NT) uw[i] = 0u;
    if (tid < 4) cam_compute(param, ws, tid, ue0, ue1, ua0, ua1);
    grid.sync();

    // ---- Phase B: projection (blocks 0..127), CNT_SIL privatized in LDS ----
    if (blockIdx.x < 128) {
        int b = blockIdx.x >> 6;
        int p = ((blockIdx.x & 63) << 8) + t;
        unsigned char* fb = (unsigned char*)(uw + FLAGS8);
        const float* P = pc + ((size_t)b * NPTS + p) * 6;
        float c0[12], c1[12];
        const float* w0 = ws + (b * 2) * 12;
        #pragma unroll
        for (int i = 0; i < 12; i++) { c0[i] = w0[i]; c1[i] = w0[12 + i]; }

        #pragma unroll
        for (int j = 0; j < 4; j++) sh[t * 4 + j] = 0u;
        __syncthreads();

        float4 q0 = project_pt(P, c0);
        ((float4*)(ws + PROJ0))[b * NPTS + p] = q0;
        int bxl, bxh, byl, byh;
        bin_bbox(q0, R_SILF, bxl, bxh, byl, byh);
        for (int by = byl; by <= byh; by++)
            for (int bx = bxl; bx <= bxh; bx++)
                atomicAdd(&sh[by * 32 + bx], 1u);

        float4 q1 = project_pt(P, c1);
        ((float4*)(ws + PROJ1))[b * NPTS + p] = q1;
        if (q1.z > 0.0f) {
            int cl, chh, rl, rh;
            pix_range(q1.x, R_DEPF, cl, chh);
            pix_range(q1.y, R_DEPF, rl, rh);
            for (int rr = rl; rr <= rh; rr++) {
                float gyv = 1.0f - (float)(2 * rr + 1) * (1.0f/128.0f);
                float dy = gyv - q1.y;
                for (int cc = cl; cc <= chh; cc++) {
                    float gxv = 1.0f - (float)(2 * cc + 1) * (1.0f/128.0f);
                    float dx = gxv - q1.x;
                    if (dx*dx + dy*dy < R2_DEP) fb[b * NPTS + rr * 128 + cc] = 1;
                }
            }
        }
        __syncthreads();
        #pragma unroll
        for (int j = 0; j < 4; j++) {
            unsigned c = sh[t * 4 + j];
            if (c) atomicAdd(&uw[CNT_SIL + b * 1024 + t * 4 + j], c);
        }
        __threadfence();
    }
    if (t == 0) shLast = (atomicAdd(&uw[TICK0], 1u) == FUSED_BLOCKS - 1) ? 1u : 0u;
    __syncthreads();
    if (shLast) {
        __threadfence();
        for (int job = 0; job < 4; job++) {
            body_area_scan(ws, job, t, sh);
            __syncthreads();
        }
        __threadfence();
    }
    grid.sync();

    // ---- Phase D: cntada (blocks 0..127) + scatsil (blocks 128..255) ----
    if (blockIdx.x < 128) {
        int b = blockIdx.x >> 6;
        int p = ((blockIdx.x & 63) << 8) + t;
        float4 q = ((const float4*)(ws + PROJ1))[b * NPTS + p];
        float pa = ws[PA_OFF + b];
        #pragma unroll
        for (int j = 0; j < 4; j++) sh[t * 4 + j] = 0u;
        __syncthreads();
        int bxl, bxh, byl, byh;
        bin_bbox(q, pa, bxl, bxh, byl, byh);
        for (int by = byl; by <= byh; by++)
            for (int bx = bxl; bx <= bxh; bx++)
                atomicAdd(&sh[by * 32 + bx], 1u);
        __syncthreads();
        #pragma unroll
        for (int j = 0; j < 4; j++) {
            unsigned c = sh[t * 4 + j];
            if (c) atomicAdd(&uw[CNT_ADA + b * 1024 + t * 4 + j], c);
        }
        __threadfence();
    } else if (blockIdx.x < 256) {
        int blk = blockIdx.x - 128;
        int b = blk >> 6;
        int p = ((blk & 63) << 8) + t;
        float4 q = ((const float4*)(ws + PROJ0))[b * NPTS + p];
        int bxl, bxh, byl, byh;
        bin_bbox(q, R_SILF, bxl, bxh, byl, byh);
        #pragma unroll
        for (int j = 0; j < 4; j++) sh[t * 4 + j] = 0u;
        __syncthreads();
        for (int by = byl; by <= byh; by++)
            for (int bx = bxl; bx <= bxh; bx++)
                atomicAdd(&sh[by * 32 + bx], 1u);
        __syncthreads();
        #pragma unroll
        for (int j = 0; j < 4; j++) {
            int bin = t * 4 + j;
            unsigned c = sh[bin];
            unsigned gb = 0;
            if (c) gb = uw[OFF_SIL + b * 1024 + bin] +
                        atomicAdd(&uw[CNT_SIL + b * 1024 + bin], c);
            sh[1024 + bin] = gb;
            sh[bin] = 0u;
        }
        __syncthreads();
        for (int by = byl; by <= byh; by++)
            for (int bx = bxl; bx <= bxh; bx++) {
                int bin = by * 32 + bx;
                unsigned loc = atomicAdd(&sh[bin], 1u);
                ((float4*)(ws + LSILF))[b * 65536 + sh[1024 + bin] + loc] = q;
            }
        __threadfence();
    }
    if (t == 0) shLast = (atomicAdd(&uw[TICK1], 1u) == FUSED_BLOCKS - 1) ? 1u : 0u;
    __syncthreads();
    if (shLast) {
        __threadfence();
        if (t < 128) body_scan_ada(ws, t >> 6, t & 63);
        __threadfence();
    }
    grid.sync();

    // ---- Phase F: scatter ada (blocks 0..127), privatized two-pass ----
    if (blockIdx.x < 128) {
        int b = blockIdx.x >> 6;
        int p = ((blockIdx.x & 63) << 8) + t;
        float4 q = ((const float4*)(ws + PROJ1))[b * NPTS + p];
        float pa = ws[PA_OFF + b];
        int bxl, bxh, byl, byh;
        bin_bbox(q, pa, bxl, bxh, byl, byh);
        #pragma unroll
        for (int j = 0; j < 4; j++) sh[t * 4 + j] = 0u;
        __syncthreads();
        for (int by = byl; by <= byh; by++)
            for (int bx = bxl; bx <= bxh; bx++)
                atomicAdd(&sh[by * 32 + bx], 1u);
        __syncthreads();
        #pragma unroll
        for (int j = 0; j < 4; j++) {
            int bin = t * 4 + j;
            unsigned c = sh[bin];
            unsigned gb = 0;
            if (c) gb = uw[OFF_ADA + b * 1024 + bin] +
                        atomicAdd(&uw[CNT_ADA + b * 1024 + bin], c);
            sh[1024 + bin] = gb;
            sh[bin] = 0u;
        }
        __syncthreads();
        for (int by = byl; by <= byh; by++)
            for (int bx = bxl; bx <= bxh; bx++) {
                int bin = by * 32 + bx;
                unsigned loc = atomicAdd(&sh[bin], 1u);
                ((float4*)(ws + LADAF))[b * 147456 + sh[1024 + bin] + loc] = q;
            }
    }
    grid.sync();

    // ---- Phase G: gather v4 — 4 tiles per block (rep-interleaved), 256 thr/tile ----
    for (int rep = 0; rep < 4; rep++) {
        int id = rep * 1024 + blockIdx.x;      // rep0=sil b0, rep1=sil b1, rep2=ada b0, rep3=ada b1
        body_gather256(ws, out, id, t, (float*)sh);
        __syncthreads();
    }
}

// ============== TIER-1 split kernels ==============

__global__ __launch_bounds__(256) void k_zero(float* __restrict__ ws) {
    unsigned* uw = (unsigned*)ws;
    int gid = blockIdx.x * 256 + threadIdx.x;
    int stride = gridDim.x * 256;
    for (int i = 48 + gid; i < ZERO_END; i += stride) uw[i] = 0u;
}

__global__ __launch_bounds__(256) void k_proj_v3(const float* __restrict__ pc,
                                                 const float* __restrict__ param,
                                                 float* __restrict__ ws,
                                                 float ue0, float ue1,
                                                 float ua0, float ua1) {
    int b = blockIdx.x >> 6;
    int p = ((blockIdx.x & 63) << 8) + threadIdx.x;
    float azim0 = param[b * 24 + 0];
    float elev0 = param[b * 24 + 3];
    float c0[12], c1[12];
    cam_calc(elev0, azim0, c0);
    float ue = b ? ue1 : ue0;
    float ua = b ? ua1 : ua0;
    cam_calc(ue * 60.0f - 30.0f, ua * 300.0f + azim0 + 30.0f, c1);

    unsigned* uw = (unsigned*)ws;
    unsigned char* fb = (unsigned char*)(uw + FLAGS8);
    const float* P = pc + ((size_t)b * NPTS + p) * 6;

    float4 q0 = project_pt(P, c0);
    ((float4*)(ws + PROJ0))[b * NPTS + p] = q0;
    int bxl, bxh, byl, byh;
    bin_bbox(q0, R_SILF, bxl, bxh, byl, byh);
    for (int by = byl; by <= byh; by++)
        for (int bx = bxl; bx <= bxh; bx++)
            atomicAdd(&uw[CNT_SIL + b * 1024 + by * 32 + bx], 1u);

    float4 q1 = project_pt(P, c1);
    ((float4*)(ws + PROJ1))[b * NPTS + p] = q1;
    if (q1.z > 0.0f) {
        int cl, chh, rl, rh;
        pix_range(q1.x, R_DEPF, cl, chh);
        pix_range(q1.y, R_DEPF, rl, rh);
        for (int rr = rl; rr <= rh; rr++) {
            float gy = 1.0f - (float)(2 * rr + 1) * (1.0f/128.0f);
            float dy = gy - q1.y;
            for (int cc = cl; cc <= chh; cc++) {
                float gx = 1.0f - (float)(2 * cc + 1) * (1.0f/128.0f);
                float dx = gx - q1.x;
                if (dx*dx + dy*dy < R2_DEP) fb[b * NPTS + rr * 128 + cc] = 1;
            }
        }
    }
}

__global__ __launch_bounds__(256) void k_area_scan_v3(float* __restrict__ ws) {
    __shared__ unsigned s[256];
    body_area_scan(ws, blockIdx.x, threadIdx.x, s);
}

__global__ __launch_bounds__(64) void k_cntada_scatsil(float* __restrict__ ws) {
    int id = blockIdx.x;
    bool isCnt = id < 512;
    int p = ((isCnt ? id : id - 512) << 6) + threadIdx.x;
    if (isCnt) body_cnt_ada(ws, p);
    else       body_scat_sil(ws, p);
}

__global__ __launch_bounds__(64) void k_scan_ada64(float* __restrict__ ws) {
    body_scan_ada(ws, blockIdx.x, threadIdx.x);
}

__global__ __launch_bounds__(64) void k_scatter_ada_v2(float* __restrict__ ws) {
    body_scat_ada(ws, (blockIdx.x << 6) + threadIdx.x);
}

__global__ __launch_bounds__(256) void k_gather_v4(const float* __restrict__ ws,
                                                   float* __restrict__ out) {
    __shared__ float sm[1024];
    body_gather256(ws, out, blockIdx.x, threadIdx.x, sm);
}

// ============== TIER-2 kernels (round-2 known-good, pid lists) ==============

__global__ __launch_bounds__(256) void k_init(const float* __restrict__ param,
                                              float* __restrict__ ws,
                                              float ue0, float ue1,
                                              float ua0, float ua1) {
    unsigned* uw = (unsigned*)ws;
    int gid = blockIdx.x * 256 + threadIdx.x;
    int stride = gridDim.x * 256;
    for (int i = gid; i < 2048; i += stride) { uw[CNT_SIL + i] = 0u; uw[CNT_ADA + i] = 0u; }
    for (int i = gid; i < 32768; i += stride) uw[FLAGS + i] = 0u;
    if (gid < 2) uw[AREA_OFF + gid] = 0u;
    if (gid < 4) cam_compute(param, ws, gid, ue0, ue1, ua0, ua1);
}

__global__ __launch_bounds__(256) void k_proj_count(const float* __restrict__ pc,
                                                    float* __restrict__ ws) {
    unsigned* uw = (unsigned*)ws;
    int b = blockIdx.x >> 6;
    int p = ((blockIdx.x & 63) << 8) + threadIdx.x;
    const float* P = pc + ((size_t)b * NPTS + p) * 6;
    float c0[12], c1[12];
    const float* w0 = ws + (b * 2) * 12;
    #pragma unroll
    for (int i = 0; i < 12; i++) { c0[i] = w0[i]; c1[i] = w0[12 + i]; }

    float4 q0 = project_pt(P, c0);
    ((float4*)(ws + PROJ0))[b * NPTS + p] = q0;
    int bxl, bxh, byl, byh;
    bin_bbox(q0, R_SILF, bxl, bxh, byl, byh);
    for (int by = byl; by <= byh; by++)
        for (int bx = bxl; bx <= bxh; bx++)
            atomicAdd(&uw[CNT_SIL + b * 1024 + by * 32 + bx], 1u);

    float4 q1 = project_pt(P, c1);
    ((float4*)(ws + PROJ1))[b * NPTS + p] = q1;
    if (q1.z > 0.0f) {
        int cl, chh, rl, rh;
        pix_range(q1.x, R_DEPF, cl, chh);
        pix_range(q1.y, R_DEPF, rl, rh);
        for (int rr = rl; rr <= rh; rr++) {
            float gy = 1.0f - (float)(2 * rr + 1) * (1.0f/128.0f);
            float dy = gy - q1.y;
            for (int cc = cl; cc <= chh; cc++) {
                float gx = 1.0f - (float)(2 * cc + 1) * (1.0f/128.0f);
                float dx = gx - q1.x;
                if (dx*dx + dy*dy < R2_DEP) uw[FLAGS + b * NPTS + rr * 128 + cc] = 1u;
            }
        }
    }
}

__global__ __launch_bounds__(256) void k_area_scan(float* __restrict__ ws) {
    unsigned* uw = (unsigned*)ws;
    __shared__ unsigned s[256];
    int t = threadIdx.x;
    int job = blockIdx.x;
    if (job < 2) {
        int b = job;
        unsigned acc = 0;
        for (int i = t; i < NPTS; i += 256) acc += uw[FLAGS + b * NPTS + i];
        s[t] = acc; __syncthreads();
        for (int off = 128; off > 0; off >>= 1) {
            if (t < off) s[t] += s[t + off];
            __syncthreads();
        }
        if (t == 0) {
            unsigned area = s[0];
            uw[AREA_OFF + b] = area;
            float pa = (float)area * (1.0f/16384.0f) * 0.057f;
            ws[PA_OFF + b] = pa;
            ws[R2ADA_OFF + b] = pa * pa;
        }
    } else {
        int b = job - 2;
        scan1024(uw, CNT_SIL + b * 1024, OFF_SIL + b * 1024, s, t);
    }
}

__global__ __launch_bounds__(256) void k_count_ada(float* __restrict__ ws) {
    int b = blockIdx.x >> 6;
    int p = ((blockIdx.x & 63) << 8) + threadIdx.x;
    body_cnt_ada(ws, b * NPTS + p);
}

__global__ __launch_bounds__(256) void k_scan_ada(float* __restrict__ ws) {
    unsigned* uw = (unsigned*)ws;
    __shared__ unsigned s[256];
    int b = blockIdx.x;
    scan1024(uw, CNT_ADA + b * 1024, OFF_ADA + b * 1024, s, threadIdx.x);
}

__global__ __launch_bounds__(256) void k_scatter(float* __restrict__ ws) {
    unsigned* uw = (unsigned*)ws;
    int b = blockIdx.x >> 6;
    int p = ((blockIdx.x & 63) << 8) + threadIdx.x;

    float4 q0 = ((const float4*)(ws + PROJ0))[b * NPTS + p];
    int bxl, bxh, byl, byh;
    bin_bbox(q0, R_SILF, bxl, bxh, byl, byh);
    for (int by = byl; by <= byh; by++)
        for (int bx = bxl; bx <= bxh; bx++) {
            unsigned bin = b * 1024 + by * 32 + bx;
            unsigned idx = uw[OFF_SIL + bin] + atomicAdd(&uw[CNT_SIL + bin], 1u);
            uw[LSIL + b * 65536 + idx] = (unsigned)p;
        }

    float4 q1 = ((const float4*)(ws + PROJ1))[b * NPTS + p];
    float pa = ws[PA_OFF + b];
    bin_bbox(q1, pa, bxl, bxh, byl, byh);
    for (int by = byl; by <= byh; by++)
        for (int bx = bxl; bx <= bxh; bx++) {
            unsigned bin = b * 1024 + by * 32 + bx;
            unsigned idx = uw[OFF_ADA + bin] + atomicAdd(&uw[CNT_ADA + bin], 1u);
            uw[LADA + b * 147456 + idx] = (unsigned)p;
        }
}

__global__ __launch_bounds__(256) void k_gather_sil(const float* __restrict__ ws,
                                                    float* __restrict__ out) {
    const unsigned* uw = (const unsigned*)ws;
    int b = blockIdx.x >> 6;
    int tile = (blockIdx.x & 63) * 16 + (threadIdx.x >> 4);
    int q = threadIdx.x & 15;
    int bx = tile & 31, by = tile >> 5;
    int col = (bx << 2) + (q & 3), row = (by << 2) + (q >> 2);
    float gx = 1.0f - (float)(2*col + 1) * (1.0f/128.0f);
    float gy = 1.0f - (float)(2*row + 1) * (1.0f/128.0f);
    unsigned start = uw[OFF_SIL + b * 1024 + tile];
    unsigned len   = uw[CNT_SIL + b * 1024 + tile];
    const float4* pr = (const float4*)(ws + PROJ0) + b * NPTS;

    float tz[8], td[8];
    #pragma unroll
    for (int k = 0; k < 8; k++) { tz[k] = INFINITY; td[k] = 0.0f; }
    for (unsigned i = 0; i < len; i++) {
        unsigned pid = uw[LSIL + b * 65536 + start + i];
        hit_test(pr[pid], gx, gy, R2_SIL, tz, td);
    }
    float trans = 1.0f, s = 0.0f;
    #pragma unroll
    for (int k = 0; k < 8; k++) {
        float a = (tz[k] != INFINITY) ? (1.0f - td[k] / R2_SIL) : 0.0f;
        s += a * trans;
        trans *= (1.0f - a);
    }
    out[(b << 14) + row * 128 + col] = s * 255.0f;
}

__global__ __launch_bounds__(256) void k_gather_ada(const float* __restrict__ ws,
                                                    float* __restrict__ out) {
    const unsigned* uw = (const unsigned*)ws;
    int b = blockIdx.x >> 6;
    int tile = (blockIdx.x & 63) * 16 + (threadIdx.x >> 4);
    int q = threadIdx.x & 15;
    int bx = tile & 31, by = tile >> 5;
    int col = (bx << 2) + (q & 3), row = (by << 2) + (q >> 2);
    float gx = 1.0f - (float)(2*col + 1) * (1.0f/128.0f);
    float gy = 1.0f - (float)(2*row + 1) * (1.0f/128.0f);
    float r2 = ws[R2ADA_OFF + b];
    unsigned start = uw[OFF_ADA + b * 1024 + tile];
    unsigned len   = uw[CNT_ADA + b * 1024 + tile];
    const float4* pr = (const float4*)(ws + PROJ1) + b * NPTS;

    float tz[8], td[8];
    #pragma unroll
    for (int k = 0; k < 8; k++) { tz[k] = INFINITY; td[k] = 0.0f; }
    for (unsigned i = 0; i < len; i++) {
        unsigned pid = uw[LADA + b * 147456 + start + i];
        hit_test(pr[pid], gx, gy, r2, tz, td);
    }
    int pix = (b << 14) + row * 128 + col;
    float* dep = out + 32768  + (size_t)pix * 8;
    float* dst = out + 294912 + (size_t)pix * 8;
    #pragma unroll
    for (int k = 0; k < 8; k++) {
        bool v = (tz[k] != INFINITY);
        dep[k] = v ? tz[k] : -1.0f;
        dst[k] = v ? td[k] : -1.0f;
    }
}

// ================= tier-3 brute-force (round-1 known-good) =================
__global__ void cam_kernel_fb(const float* __restrict__ param, float* __restrict__ ws,
                              float ue0, float ue1, float ua0, float ua1) {
    int t = threadIdx.x;
    if (t < 2) ws[48 + t] = 0.0f;
    if (t >= 4) return;
    cam_compute(param, ws, t, ue0, ue1, ua0, ua1);
}

__device__ __forceinline__ void stage_points(const float* __restrict__ pcb,
                                             const float c[12], int c0, float4* sp) {
    for (int i = threadIdx.x; i < CH; i += 256) {
        const float* P = pcb + (size_t)(c0 + i) * 6;
        sp[i] = project_pt(P, c);
    }
}

__global__ __launch_bounds__(256) void raster_AB(const float* __restrict__ pc,
                                                 float* __restrict__ ws,
                                                 float* __restrict__ out) {
    __shared__ float4 sp[CH];
    int bid = blockIdx.x;
    bool silMode = bid < 128;
    int q = silMode ? bid : bid - 128;
    int b = q >> 6;
    int p = ((q & 63) << 8) + threadIdx.x;
    const float* cw = ws + (b * 2 + (silMode ? 0 : 1)) * 12;
    float c[12];
    #pragma unroll
    for (int i = 0; i < 12; i++) c[i] = cw[i];
    float r2 = silMode ? R2_SIL : R2_DEP;
    int col = p & 127, row = p >> 7;
    float gx = 1.0f - (float)(2*col + 1) * (1.0f/128.0f);
    float gy = 1.0f - (float)(2*row + 1) * (1.0f/128.0f);
    const float* pcb = pc + (size_t)b * NPTS * 6;

    if (silMode) {
        float tz[8], td[8];
        #pragma unroll
        for (int k = 0; k < 8; k++) { tz[k] = INFINITY; td[k] = 0.0f; }
        for (int c0 = 0; c0 < NPTS; c0 += CH) {
            __syncthreads();
            stage_points(pcb, c, c0, sp);
            __syncthreads();
            #pragma unroll 4
            for (int j = 0; j < CH; j++) hit_test(sp[j], gx, gy, r2, tz, td);
        }
        float trans = 1.0f, s = 0.0f;
        #pragma unroll
        for (int k = 0; k < 8; k++) {
            float a = (tz[k] != INFINITY) ? (1.0f - td[k] / r2) : 0.0f;
            s += a * trans;
            trans *= (1.0f - a);
        }
        out[(b << 14) + p] = s * 255.0f;
    } else {
        float mz = INFINITY;
        for (int c0 = 0; c0 < NPTS; c0 += CH) {
            __syncthreads();
            stage_points(pcb, c, c0, sp);
            __syncthreads();
            #pragma unroll 4
            for (int j = 0; j < CH; j++) {
                float4 pt = sp[j];
                float dx = gx - pt.x, dy = gy - pt.y;
                float d2 = dx*dx + dy*dy;
                if (d2 < r2 && pt.z > 0.0f) mz = fminf(mz, pt.z);
            }
        }
        unsigned long long m = __ballot(mz != INFINITY);
        if ((threadIdx.x & 63) == 0)
            atomicAdd(ws + 48 + b, (float)__popcll(m));
    }
}

__global__ __launch_bounds__(256) void raster_C(const float* __restrict__ pc,
                                                const float* __restrict__ ws,
                                                float* __restrict__ out) {
    __shared__ float4 sp[CH];
    int bid = blockIdx.x;
    int b = bid >> 6;
    int p = ((bid & 63) << 8) + threadIdx.x;
    const float* cw = ws + (b * 2 + 1) * 12;
    float c[12];
    #pragma unroll
    for (int i = 0; i < 12; i++) c[i] = cw[i];
    float area = ws[48 + b];
    float pa = (area * (1.0f/16384.0f)) * 0.057f;
    float r2 = pa * pa;
    int col = p & 127, row = p >> 7;
    float gx = 1.0f - (float)(2*col + 1) * (1.0f/128.0f);
    float gy = 1.0f - (float)(2*row + 1) * (1.0f/128.0f);
    const float* pcb = pc + (size_t)b * NPTS * 6;

    float tz[8], td[8];
    #pragma unroll
    for (int k = 0; k < 8; k++) { tz[k] = INFINITY; td[k] = 0.0f; }
    for (int c0 = 0; c0 < NPTS; c0 += CH) {
        __syncthreads();
        stage_points(pcb, c, c0, sp);
        __syncthreads();
        #pragma unroll 4
        for (int j = 0; j < CH; j++) hit_test(sp[j], gx, gy, r2, tz, td);
    }
    float* dep = out + 32768  + (size_t)((b << 14) + p) * 8;
    float* dst = out + 294912 + (size_t)((b << 14) + p) * 8;
    #pragma unroll
    for (int k = 0; k < 8; k++) {
        bool v = (tz[k] != INFINITY);
        dep[k] = v ? tz[k] : -1.0f;
        dst[k] = v ? td[k] : -1.0f;
    }
}

// ---------------- host-side threefry2x32-20 (JAX-compatible) ----------------
static inline uint32_t rotl32(uint32_t x, int r) { return (x << r) | (x >> (32 - r)); }

static void tf2x32(uint32_t k0, uint32_t k1, uint32_t c0, uint32_t c1,
                   uint32_t* o0, uint32_t* o1) {
    uint32_t ks0 = k0, ks1 = k1, ks2 = k0 ^ k1 ^ 0x1BD11BDAu;
    uint32_t x0 = c0 + ks0, x1 = c1 + ks1;
    static const int rA[4] = {13, 15, 26, 6};
    static const int rB[4] = {17, 29, 16, 24};
    #define RND4(R) do { for (int i = 0; i < 4; i++) { x0 += x1; x1 = rotl32(x1, R[i]); x1 ^= x0; } } while (0)
    RND4(rA); x0 += ks1; x1 += ks2 + 1u;
    RND4(rB); x0 += ks2; x1 += ks0 + 2u;
    RND4(rA); x0 += ks0; x1 += ks1 + 3u;
    RND4(rB); x0 += ks1; x1 += ks2 + 4u;
    RND4(rA); x0 += ks2; x1 += ks0 + 5u;
    #undef RND4
    *o0 = x0; *o1 = x1;
}

static inline float bits_to_unit_float(uint32_t bits) {
    uint32_t fb = (bits >> 9) | 0x3f800000u;
    float f;
    memcpy(&f, &fb, 4);
    return f - 1.0f;
}

extern "C" void kernel_launch(void* const* d_in, const int* in_sizes, int n_in,
                              void* d_out, int out_size, void* d_ws, size_t ws_size,
                              hipStream_t stream) {
    const float* pc    = (const float*)d_in[0];
    const float* param = (const float*)d_in[1];
    float* out = (float*)d_out;
    float* ws  = (float*)d_ws;

    uint32_t ke0, ke1, ka0, ka1, b1, b2;
    tf2x32(0u, 42u, 0u, 0u, &ke0, &ke1);
    tf2x32(0u, 42u, 0u, 1u, &ka0, &ka1);
    float ue[2], ua[2];
    for (uint32_t i = 0; i < 2; i++) {
        tf2x32(ke0, ke1, 0u, i, &b1, &b2);
        ue[i] = bits_to_unit_float(b1 ^ b2);
        tf2x32(ka0, ka1, 0u, i, &b1, &b2);
        ua[i] = bits_to_unit_float(b1 ^ b2);
    }
    float ue0 = ue[0], ue1 = ue[1], ua0 = ua[0], ua1 = ua[1];

    if (ws_size >= WS1_NEEDED) {
        int dev = 0;
        hipGetDevice(&dev);
        hipDeviceProp_t prop;
        bool coop = (hipGetDeviceProperties(&prop, dev) == hipSuccess) &&
                    prop.cooperativeLaunch;
        if (coop) {
            int maxB = 0;
            if (hipOccupancyMaxActiveBlocksPerMultiprocessor(&maxB, k_fusedp, 256, 0)
                    != hipSuccess ||
                maxB * prop.multiProcessorCount < FUSED_BLOCKS)
                coop = false;
        }
        if (coop) {
            void* args[] = { (void*)&pc, (void*)&param, (void*)&ws, (void*)&out,
                             (void*)&ue0, (void*)&ue1, (void*)&ua0, (void*)&ua1 };
            hipError_t e = hipLaunchCooperativeKernel((const void*)k_fusedp,
                                                      dim3(FUSED_BLOCKS), dim3(256),
                                                      args, 0, stream);
            if (e == hipSuccess) return;
        }
        // tier-1 split path
        k_zero          <<<16, 256, 0, stream>>>(ws);
        k_proj_v3       <<<128, 256, 0, stream>>>(pc, param, ws, ue0, ue1, ua0, ua1);
        k_area_scan_v3  <<<4, 256, 0, stream>>>(ws);
        k_cntada_scatsil<<<1024, 64, 0, stream>>>(ws);
        k_scan_ada64    <<<2, 64, 0, stream>>>(ws);
        k_scatter_ada_v2<<<512, 64, 0, stream>>>(ws);
        k_gather_v4     <<<4096, 256, 0, stream>>>(ws, out);
    } else if (ws_size >= WS2_NEEDED) {
        k_init      <<<64, 256, 0, stream>>>(param, ws, ue0, ue1, ua0, ua1);
        k_proj_count<<<128, 256, 0, stream>>>(pc, ws);
        k_area_scan <<<4, 256, 0, stream>>>(ws);
        k_count_ada <<<128, 256, 0, stream>>>(ws);
        k_scan_ada  <<<2, 256, 0, stream>>>(ws);
        k_scatter   <<<128, 256, 0, stream>>>(ws);
        k_gather_sil<<<128, 256, 0, stream>>>(ws, out);
        k_gather_ada<<<128, 256, 0, stream>>>(ws, out);
    } else {
        cam_kernel_fb<<<1, 64, 0, stream>>>(param, ws, ue0, ue1, ua0, ua1);
        raster_AB<<<256, 256, 0, stream>>>(pc, ws, out);
        raster_C <<<128, 256, 0, stream>>>(pc, ws, out);
    }
}